// Round 3
// baseline (1356.633 us; speedup 1.0000x reference)
//
#include <hip/hip_runtime.h>
#include <cstdio>

#define DIN   1024
#define DHID  4096
#define DOUT  1024
#define NEXP  16
#define NTOK  8192
#define NPAIR (NTOK * 2)
#define PADMAX 20480          // 16384 + 16*255 rounded up to 256
#define MAXTILES 80           // max sum of per-expert ceil(cnt/256)

typedef _Float16 h8 __attribute__((ext_vector_type(8)));
typedef _Float16 h4 __attribute__((ext_vector_type(4)));
typedef float    f4 __attribute__((ext_vector_type(4)));

// ctrl[] int indices
#define C_CNT  0    // [16] per-expert pair counts
#define C_POFF 16   // [16] padded segment offsets
#define C_CUR  32   // [16] assignment cursors
#define C_NT   48   // total tiles
#define C_TE   64   // [80] tile -> expert
#define C_TP   256  // [80] tile -> p0 (padded row start)

__device__ __forceinline__ void async16(const void* g, void* l) {
  __builtin_amdgcn_global_load_lds((const __attribute__((address_space(1))) void*)g,
                                   (__attribute__((address_space(3))) void*)l, 16, 0, 0);
}

// ---- init: zero out, convert x->fp16, default perm, zero ctrl ----
__global__ void k_init(float* __restrict__ out, const float* __restrict__ x,
                       _Float16* __restrict__ x16, int* __restrict__ ptok,
                       float* __restrict__ pw, int* __restrict__ ctrl) {
  int i = blockIdx.x * 256 + threadIdx.x;           // 2,097,152 threads
  ((f4*)out)[i] = (f4){0.f, 0.f, 0.f, 0.f};
  float4 v = ((const float4*)x)[i];
  h4 hv = {(_Float16)v.x, (_Float16)v.y, (_Float16)v.z, (_Float16)v.w};
  ((h4*)x16)[i] = hv;
  if (i < PADMAX) { ptok[i] = 0; pw[i] = 0.f; }
  if (i < 1024) ctrl[i] = 0;
}

// ---- gating: logits, top-2, softmax weights, counts. 1 wave/token ----
__global__ void k_gate(const float* __restrict__ x, const float* __restrict__ wg,
                       int* __restrict__ te, float* __restrict__ tw,
                       int* __restrict__ ctrl) {
  int t = blockIdx.x * 4 + (threadIdx.x >> 6);
  int l = threadIdx.x & 63;
  const float* xr = x + (long)t * DIN;
  float acc[NEXP];
#pragma unroll
  for (int e = 0; e < NEXP; ++e) acc[e] = 0.f;
  for (int k = l; k < DIN; k += 64) {
    float xv = xr[k];
    const float4* wr = (const float4*)(wg + (long)k * NEXP);
    float4 a = wr[0], b = wr[1], c = wr[2], d = wr[3];
    acc[0]  += xv * a.x; acc[1]  += xv * a.y; acc[2]  += xv * a.z; acc[3]  += xv * a.w;
    acc[4]  += xv * b.x; acc[5]  += xv * b.y; acc[6]  += xv * b.z; acc[7]  += xv * b.w;
    acc[8]  += xv * c.x; acc[9]  += xv * c.y; acc[10] += xv * c.z; acc[11] += xv * c.w;
    acc[12] += xv * d.x; acc[13] += xv * d.y; acc[14] += xv * d.z; acc[15] += xv * d.w;
  }
#pragma unroll
  for (int off = 32; off > 0; off >>= 1) {
#pragma unroll
    for (int e = 0; e < NEXP; ++e) acc[e] += __shfl_xor(acc[e], off, 64);
  }
  if (l == 0) {
    float v0 = -1e30f; int e0 = 0;
#pragma unroll
    for (int e = 0; e < NEXP; ++e) if (acc[e] > v0) { v0 = acc[e]; e0 = e; }
    float v1 = -1e30f; int e1 = 0;
#pragma unroll
    for (int e = 0; e < NEXP; ++e) if (e != e0 && acc[e] > v1) { v1 = acc[e]; e1 = e; }
    float d = expf(v1 - v0);
    float den = 1.f / (1.f + d);
    te[2 * t] = e0;     tw[2 * t] = den;       // w0 (top-1)
    te[2 * t + 1] = e1; tw[2 * t + 1] = d * den;
    atomicAdd(&ctrl[C_CNT + e0], 1);
    atomicAdd(&ctrl[C_CNT + e1], 1);
  }
}

// ---- scan: padded offsets (256-granular), cursors, tile table ----
__global__ void k_scan(int* __restrict__ ctrl) {
  __shared__ int sOff[NEXP], sT0[NEXP], sTiles[NEXP];
  int tid = threadIdx.x;
  if (tid == 0) {
    int off = 0, nt = 0;
    for (int e = 0; e < NEXP; ++e) {
      int c = ctrl[C_CNT + e];
      int tiles = (c + 255) >> 8;
      ctrl[C_POFF + e] = off;
      ctrl[C_CUR + e] = off;
      sOff[e] = off; sT0[e] = nt; sTiles[e] = tiles;
      nt += tiles;
      off += tiles * 256;
    }
    ctrl[C_NT] = nt;
  }
  __syncthreads();
  int nt = sT0[NEXP - 1] + sTiles[NEXP - 1];
  for (int j = tid; j < nt; j += blockDim.x) {
    int e = 0;
#pragma unroll
    for (int k = 1; k < NEXP; ++k) if (j >= sT0[k]) e = k;
    ctrl[C_TE + j] = e;
    ctrl[C_TP + j] = sOff[e] + (j - sT0[e]) * 256;
  }
}

// ---- assign: fill permuted pair arrays ----
__global__ void k_assign(const int* __restrict__ te, const float* __restrict__ tw,
                         int* __restrict__ ctrl, int* __restrict__ ptok,
                         float* __restrict__ pw) {
  int t = blockIdx.x * 256 + threadIdx.x;
#pragma unroll
  for (int s = 0; s < 2; ++s) {
    int e = te[2 * t + s];
    int pos = atomicAdd(&ctrl[C_CUR + e], 1);
    ptok[pos] = t;
    pw[pos] = tw[2 * t + s];
  }
}

// ---- transpose+convert: W [E][R][C] fp32 -> out [E][C][R] fp16, 128x64 tiles ----
__global__ void k_transpose(const float* __restrict__ W, _Float16* __restrict__ out,
                            int R, int C) {
  __shared__ __align__(16) _Float16 tile[64][136];
  int e = blockIdx.z;
  const float* Wb = W + ((long)e * R + blockIdx.x * 128) * C + blockIdx.y * 64;
  int tid = threadIdx.x;
  int rr = tid >> 4;          // 0..15
  int cc = (tid & 15) * 4;    // 0..60
#pragma unroll
  for (int i = 0; i < 8; ++i) {
    int r = rr + i * 16;
    float4 v = *(const float4*)(Wb + (long)r * C + cc);
    tile[cc + 0][r] = (_Float16)v.x;
    tile[cc + 1][r] = (_Float16)v.y;
    tile[cc + 2][r] = (_Float16)v.z;
    tile[cc + 3][r] = (_Float16)v.w;
  }
  __syncthreads();
  _Float16* ob = out + ((long)e * C + blockIdx.y * 64) * R + blockIdx.x * 128;
  int c2 = tid >> 4;          // 0..15
  int ch = tid & 15;          // 0..15
#pragma unroll
  for (int i = 0; i < 4; ++i) {
    int c = c2 + i * 16;
    *(h8*)(ob + (long)c * R + ch * 8) = *(const h8*)&tile[c][ch * 8];
  }
}

// ---- grouped GEMM: 256x256 tile, BK=64, 8 waves (2Mx4N), 8-phase schedule ----
// Split-K (KP parts) for tail-size control; 1D grid with bijective XCD chunk
// swizzle; work order (nb,kp)-major, mt-fastest so one XCD's co-resident blocks
// share the same 512KB B K-slice in its L2.
// T3+T4: counted vmcnt(6) once per K-tile; T5: setprio around MFMA clusters.
// LDS 128 KiB: 2 dbuf x {A,B} x 2 halves x 128x64 fp16. XOR swizzle on global
// source chunk (c ^= r&7); linear global_load_lds dest; same XOR on ds_read.
template<int KD, int ND, int G1, int KP>
__global__ __launch_bounds__(512, 2)
void k_gemm(const _Float16* __restrict__ A, const _Float16* __restrict__ Wt,
            const float* __restrict__ bias, const int* __restrict__ ctrl,
            const int* __restrict__ ptok, const float* __restrict__ pw,
            _Float16* __restrict__ Hout, float* __restrict__ out) {
  __shared__ __align__(16) _Float16 sm[65536];   // 128 KB

  // work decode: grid.x = (ND/256)*KP*MAXTILES = 1280 for both GEMMs
  constexpr int NW = (ND / 256) * KP * MAXTILES;
  constexpr int QX = NW / 8;                     // 160, chunk per XCD
  int bid = blockIdx.x;
  int wid = (bid & 7) * QX + (bid >> 3);         // bijective XCD chunk swizzle
  int mt = wid % MAXTILES;
  int g  = wid / MAXTILES;
  int kp = (KP > 1) ? (g % KP) : 0;
  int nb = g / KP;

  if (mt >= ctrl[C_NT]) return;
  int e  = ctrl[C_TE + mt];
  int p0 = ctrl[C_TP + mt];
  int n0 = nb * 256;
  long kbase = (long)kp * (KD / KP);
  int tid = threadIdx.x;
  int w = tid >> 6, l = tid & 63;
  int wm = w & 1, wn = w >> 1;           // 2 M-warps x 4 N-warps
  int ln15 = l & 15, lq = l >> 4;

  // ---- staging pointers: per (tensor, half, slot j) ----
  const _Float16* agp[4];   // [half*2+j]
  const _Float16* bgp[4];
#pragma unroll
  for (int h = 0; h < 2; ++h)
#pragma unroll
    for (int j = 0; j < 2; ++j) {
      int r = (w * 2 + j) * 8 + (l >> 3);          // row in half, 0..127
      int c = (l & 7) ^ (r & 7);
      long arow = G1 ? (long)ptok[p0 + h * 128 + r] : (long)(p0 + h * 128 + r);
      agp[h * 2 + j] = A + arow * KD + kbase + c * 8;
      bgp[h * 2 + j] = Wt + ((long)e * ND + n0 + h * 128 + r) * KD + kbase + c * 8;
    }

  // half ids: 0=A0 1=B0 2=A1 3=B1 (stage order within a tile)
  auto stageH = [&](int t, int half) {
    _Float16* dst = sm + (t & 1) * 32768 + (half & 1) * 16384 + (half >> 1) * 8192
                    + w * 1024;
    long koff = (long)t * 64;
    const _Float16* const* gp = (half & 1) ? bgp : agp;
#pragma unroll
    for (int j = 0; j < 2; ++j)
      async16(gp[(half >> 1) * 2 + j] + koff, dst + j * 512);
  };

  f4 acc[2][4][2][2];
#pragma unroll
  for (int mq = 0; mq < 2; ++mq)
#pragma unroll
    for (int i = 0; i < 4; ++i)
#pragma unroll
      for (int nq = 0; nq < 2; ++nq)
#pragma unroll
        for (int j = 0; j < 2; ++j) acc[mq][i][nq][j] = (f4){0.f, 0.f, 0.f, 0.f};

  h8 af[8], bf0[4], bf1[4];

  auto readA = [&](int d, int mq) {     // 8 x ds_read_b128
    const _Float16* Ab = sm + d * 32768 + mq * 8192;
#pragma unroll
    for (int i = 0; i < 4; ++i) {
      int rh = wm * 64 + i * 16 + ln15;
#pragma unroll
      for (int ks = 0; ks < 2; ++ks)
        af[i * 2 + ks] = *(const h8*)&Ab[rh * 64 + (((ks * 4 + lq)) ^ (rh & 7)) * 8];
    }
  };
  auto readB = [&](int d, int nq, h8* bf) {   // 4 x ds_read_b128
    const _Float16* Bb = sm + d * 32768 + 16384 + nq * 8192;
#pragma unroll
    for (int j = 0; j < 2; ++j) {
      int rh = wn * 32 + j * 16 + ln15;
#pragma unroll
      for (int ks = 0; ks < 2; ++ks)
        bf[j * 2 + ks] = *(const h8*)&Bb[rh * 64 + (((ks * 4 + lq)) ^ (rh & 7)) * 8];
    }
  };
  auto mfmaQ = [&](int mq, int nq, const h8* bf) {  // 16 MFMA = one C-quadrant
    __builtin_amdgcn_s_setprio(1);
#pragma unroll
    for (int ks = 0; ks < 2; ++ks)
#pragma unroll
      for (int i = 0; i < 4; ++i)
#pragma unroll
        for (int j = 0; j < 2; ++j)
          acc[mq][i][nq][j] = __builtin_amdgcn_mfma_f32_16x16x32_f16(
              af[i * 2 + ks], bf[j * 2 + ks], acc[mq][i][nq][j], 0, 0, 0);
    __builtin_amdgcn_s_setprio(0);
  };

  constexpr int KSTEPS = KD / 64 / KP;      // 16 for both GEMMs

  // prologue: tile0 (4 halves) + tile1 (3 halves) = 14 loads/wave in flight
  stageH(0, 0); stageH(0, 1); stageH(0, 2); stageH(0, 3);
  stageH(1, 0); stageH(1, 1); stageH(1, 2);
  asm volatile("s_waitcnt vmcnt(6)" ::: "memory");   // tile0 landed, 3 halves in flight
  __builtin_amdgcn_s_barrier();

#pragma unroll 2
  for (int t = 0; t < KSTEPS; ++t) {
    int d = t & 1;
    // P1: quadrant (mq0,nq0) — needs A0,B0 (earliest staged)
    readA(d, 0);
    readB(d, 0, bf0);
    if (t + 1 < KSTEPS) stageH(t + 1, 3);            // B1 of next tile
    __builtin_amdgcn_s_barrier();
    asm volatile("s_waitcnt lgkmcnt(0)" ::: "memory");
    mfmaQ(0, 0, bf0);
    __builtin_amdgcn_s_barrier();
    // P2: (mq0,nq1) — needs B1; A0 retired -> stage t+2 A0 in place
    readB(d, 1, bf1);
    if (t + 2 < KSTEPS) stageH(t + 2, 0);
    __builtin_amdgcn_s_barrier();
    asm volatile("s_waitcnt lgkmcnt(0)" ::: "memory");
    mfmaQ(0, 1, bf1);
    __builtin_amdgcn_s_barrier();
    // P3: (mq1,nq1) — needs A1; B0 retired -> stage t+2 B0
    readA(d, 1);
    if (t + 2 < KSTEPS) stageH(t + 2, 1);
    __builtin_amdgcn_s_barrier();
    asm volatile("s_waitcnt lgkmcnt(0)" ::: "memory");
    mfmaQ(1, 1, bf1);
    __builtin_amdgcn_s_barrier();
    // P4: (mq1,nq0) — reuses af/bf0; A1 retired -> stage t+2 A1; counted wait
    if (t + 2 < KSTEPS) stageH(t + 2, 2);
    if (t + 1 < KSTEPS) {
      if (t + 2 < KSTEPS) asm volatile("s_waitcnt vmcnt(6)" ::: "memory");
      else                asm volatile("s_waitcnt vmcnt(0)" ::: "memory");
    }
    __builtin_amdgcn_s_barrier();
    mfmaQ(1, 0, bf0);
    __builtin_amdgcn_s_barrier();
  }

  // ---- epilogue ----
  float bj[2][2];
#pragma unroll
  for (int nq = 0; nq < 2; ++nq)
#pragma unroll
    for (int j = 0; j < 2; ++j)
      bj[nq][j] = bias[e * ND + n0 + nq * 128 + wn * 32 + j * 16 + ln15];
  if (KP > 1 && kp != 0) {            // split-K: only part 0 adds bias
#pragma unroll
    for (int nq = 0; nq < 2; ++nq)
#pragma unroll
      for (int j = 0; j < 2; ++j) bj[nq][j] = 0.f;
  }

  if (G1) {
    // LDS-bounce (reuse sm): two 128-row halves, [128][264] fp16 padded
    _Float16* cs = sm;
#pragma unroll
    for (int mq = 0; mq < 2; ++mq) {
      if (mq) __syncthreads();
#pragma unroll
      for (int i = 0; i < 4; ++i)
#pragma unroll
        for (int reg = 0; reg < 4; ++reg) {
          int row = wm * 64 + i * 16 + lq * 4 + reg;
#pragma unroll
          for (int nq = 0; nq < 2; ++nq)
#pragma unroll
            for (int j = 0; j < 2; ++j)
              cs[row * 264 + nq * 128 + wn * 32 + j * 16 + ln15] =
                  (_Float16)fmaxf(acc[mq][i][nq][j][reg] + bj[nq][j], 0.f);
        }
      __syncthreads();
#pragma unroll
      for (int p = 0; p < 8; ++p) {
        int idx = p * 512 + tid;          // 128 rows x 32 h8-chunks
        int row = idx >> 5, ch = idx & 31;
        *(h8*)(Hout + (long)(p0 + mq * 128 + row) * DHID + n0 + ch * 8) =
            *(const h8*)&cs[row * 264 + ch * 8];
      }
    }
  } else {
#pragma unroll
    for (int mq = 0; mq < 2; ++mq)
#pragma unroll
      for (int i = 0; i < 4; ++i)
#pragma unroll
        for (int reg = 0; reg < 4; ++reg) {
          int p = p0 + mq * 128 + wm * 64 + i * 16 + lq * 4 + reg;
          float wgt = pw[p];
          if (wgt != 0.f) {
            int tk = ptok[p];
            float* orow = out + (long)tk * DOUT + n0;
#pragma unroll
            for (int nq = 0; nq < 2; ++nq)
#pragma unroll
              for (int j = 0; j < 2; ++j)
                atomicAdd(&orow[nq * 128 + wn * 32 + j * 16 + ln15],
                          wgt * (acc[mq][i][nq][j][reg] + bj[nq][j]));
          }
        }
  }
}

extern "C" void kernel_launch(void* const* d_in, const int* in_sizes, int n_in,
                              void* d_out, int out_size, void* d_ws, size_t ws_size,
                              hipStream_t stream) {
  const float* x  = (const float*)d_in[0];
  const float* Wg = (const float*)d_in[1];
  const float* W1 = (const float*)d_in[2];
  const float* b1 = (const float*)d_in[3];
  const float* W2 = (const float*)d_in[4];
  const float* b2 = (const float*)d_in[5];
  float* out = (float*)d_out;
  char* ws = (char*)d_ws;

  size_t WT_OFF = 0;                                   // fp16 W^T (reused W1 then W2)
  size_t H_OFF  = WT_OFF + (size_t)NEXP * DHID * DIN * 2;   // 134,217,728
  size_t X_OFF  = H_OFF  + (size_t)PADMAX * DHID * 2;       // +167,772,160
  size_t TE_OFF = X_OFF  + (size_t)NTOK * DIN * 2;          // +16,777,216
  size_t TW_OFF = TE_OFF + (size_t)NPAIR * 4;
  size_t PT_OFF = TW_OFF + (size_t)NPAIR * 4;
  size_t PW_OFF = PT_OFF + (size_t)PADMAX * 4;
  size_t CT_OFF = PW_OFF + (size_t)PADMAX * 4;
  size_t END    = CT_OFF + 4096;
  if (ws_size < END) {
    fprintf(stderr, "kernel_launch: ws too small (%zu < %zu)\n", ws_size, END);
    return;
  }
  _Float16* Wt  = (_Float16*)(ws + WT_OFF);
  _Float16* H   = (_Float16*)(ws + H_OFF);
  _Float16* x16 = (_Float16*)(ws + X_OFF);
  int*   te   = (int*)(ws + TE_OFF);
  float* tw   = (float*)(ws + TW_OFF);
  int*   pt   = (int*)(ws + PT_OFF);
  float* pw   = (float*)(ws + PW_OFF);
  int*   ctrl = (int*)(ws + CT_OFF);

  k_init<<<NTOK * DIN / (256 * 4), 256, 0, stream>>>(out, x, x16, pt, pw, ctrl);
  k_gate<<<NTOK / 4, 256, 0, stream>>>(x, Wg, te, tw, ctrl);
  k_scan<<<1, 256, 0, stream>>>(ctrl);
  k_assign<<<NTOK / 256, 256, 0, stream>>>(te, tw, ctrl, pt, pw);

  // W1 [E][1024][4096] -> Wt [E][4096][1024] fp16
  k_transpose<<<dim3(DIN / 128, DHID / 64, NEXP), 256, 0, stream>>>(W1, Wt, DIN, DHID);
  // G1: works = 16 nb * 1 kp * 80 mt = 1280
  k_gemm<DIN, DHID, 1, 1><<<dim3((DHID / 256) * MAXTILES), 512, 0, stream>>>(
      x16, Wt, b1, ctrl, pt, pw, H, nullptr);

  // W2 [E][4096][1024] -> Wt [E][1024][4096] fp16 (region reuse; stream-ordered)
  k_transpose<<<dim3(DHID / 128, DOUT / 64, NEXP), 256, 0, stream>>>(W2, Wt, DHID, DOUT);
  // G2: works = 4 nb * 4 kp * 80 mt = 1280 (split-K x4, tail ~24us)
  k_gemm<DHID, DOUT, 0, 4><<<dim3((DOUT / 256) * 4 * MAXTILES), 512, 0, stream>>>(
      H, Wt, b2, ctrl, pt, pw, nullptr, out);
}

// Round 4
// 1278.475 us; speedup vs baseline: 1.0611x; 1.0611x over previous
//
#include <hip/hip_runtime.h>
#include <cstdio>

#define DIN   1024
#define DHID  4096
#define DOUT  1024
#define NEXP  16
#define NTOK  8192
#define NPAIR (NTOK * 2)
#define PADMAX 20480          // 16384 + 16*255 rounded up to 256
#define MAXTILES 80           // max sum of per-expert ceil(cnt/256)

typedef _Float16 h8 __attribute__((ext_vector_type(8)));
typedef _Float16 h4 __attribute__((ext_vector_type(4)));
typedef float    f4 __attribute__((ext_vector_type(4)));

// ctrl[] int indices
#define C_CNT  0    // [16] per-expert pair counts
#define C_POFF 16   // [16] padded segment offsets
#define C_CUR  32   // [16] assignment cursors
#define C_NT   48   // total tiles
#define C_TE   64   // [80] tile -> expert
#define C_TP   256  // [80] tile -> p0 (padded row start)

__device__ __forceinline__ void async16(const void* g, void* l) {
  __builtin_amdgcn_global_load_lds((const __attribute__((address_space(1))) void*)g,
                                   (__attribute__((address_space(3))) void*)l, 16, 0, 0);
}

// ---- init: zero out, convert x->fp16, default perm, zero ctrl ----
__global__ void k_init(float* __restrict__ out, const float* __restrict__ x,
                       _Float16* __restrict__ x16, int* __restrict__ ptok,
                       float* __restrict__ pw, int* __restrict__ ctrl) {
  int i = blockIdx.x * 256 + threadIdx.x;           // 2,097,152 threads
  ((f4*)out)[i] = (f4){0.f, 0.f, 0.f, 0.f};
  float4 v = ((const float4*)x)[i];
  h4 hv = {(_Float16)v.x, (_Float16)v.y, (_Float16)v.z, (_Float16)v.w};
  ((h4*)x16)[i] = hv;
  if (i < PADMAX) { ptok[i] = 0; pw[i] = 0.f; }
  if (i < 1024) ctrl[i] = 0;
}

// ---- gating: logits, top-2, softmax weights, counts. 1 wave/token ----
__global__ void k_gate(const float* __restrict__ x, const float* __restrict__ wg,
                       int* __restrict__ te, float* __restrict__ tw,
                       int* __restrict__ ctrl) {
  int t = blockIdx.x * 4 + (threadIdx.x >> 6);
  int l = threadIdx.x & 63;
  const float* xr = x + (long)t * DIN;
  float acc[NEXP];
#pragma unroll
  for (int e = 0; e < NEXP; ++e) acc[e] = 0.f;
  for (int k = l; k < DIN; k += 64) {
    float xv = xr[k];
    const float4* wr = (const float4*)(wg + (long)k * NEXP);
    float4 a = wr[0], b = wr[1], c = wr[2], d = wr[3];
    acc[0]  += xv * a.x; acc[1]  += xv * a.y; acc[2]  += xv * a.z; acc[3]  += xv * a.w;
    acc[4]  += xv * b.x; acc[5]  += xv * b.y; acc[6]  += xv * b.z; acc[7]  += xv * b.w;
    acc[8]  += xv * c.x; acc[9]  += xv * c.y; acc[10] += xv * c.z; acc[11] += xv * c.w;
    acc[12] += xv * d.x; acc[13] += xv * d.y; acc[14] += xv * d.z; acc[15] += xv * d.w;
  }
#pragma unroll
  for (int off = 32; off > 0; off >>= 1) {
#pragma unroll
    for (int e = 0; e < NEXP; ++e) acc[e] += __shfl_xor(acc[e], off, 64);
  }
  if (l == 0) {
    float v0 = -1e30f; int e0 = 0;
#pragma unroll
    for (int e = 0; e < NEXP; ++e) if (acc[e] > v0) { v0 = acc[e]; e0 = e; }
    float v1 = -1e30f; int e1 = 0;
#pragma unroll
    for (int e = 0; e < NEXP; ++e) if (e != e0 && acc[e] > v1) { v1 = acc[e]; e1 = e; }
    float d = expf(v1 - v0);
    float den = 1.f / (1.f + d);
    te[2 * t] = e0;     tw[2 * t] = den;       // w0 (top-1)
    te[2 * t + 1] = e1; tw[2 * t + 1] = d * den;
    atomicAdd(&ctrl[C_CNT + e0], 1);
    atomicAdd(&ctrl[C_CNT + e1], 1);
  }
}

// ---- scan: padded offsets (256-granular), cursors, tile table ----
__global__ void k_scan(int* __restrict__ ctrl) {
  __shared__ int sOff[NEXP], sT0[NEXP], sTiles[NEXP];
  int tid = threadIdx.x;
  if (tid == 0) {
    int off = 0, nt = 0;
    for (int e = 0; e < NEXP; ++e) {
      int c = ctrl[C_CNT + e];
      int tiles = (c + 255) >> 8;
      ctrl[C_POFF + e] = off;
      ctrl[C_CUR + e] = off;
      sOff[e] = off; sT0[e] = nt; sTiles[e] = tiles;
      nt += tiles;
      off += tiles * 256;
    }
    ctrl[C_NT] = nt;
  }
  __syncthreads();
  int nt = sT0[NEXP - 1] + sTiles[NEXP - 1];
  for (int j = tid; j < nt; j += blockDim.x) {
    int e = 0;
#pragma unroll
    for (int k = 1; k < NEXP; ++k) if (j >= sT0[k]) e = k;
    ctrl[C_TE + j] = e;
    ctrl[C_TP + j] = sOff[e] + (j - sT0[e]) * 256;
  }
}

// ---- assign: fill permuted pair arrays ----
__global__ void k_assign(const int* __restrict__ te, const float* __restrict__ tw,
                         int* __restrict__ ctrl, int* __restrict__ ptok,
                         float* __restrict__ pw) {
  int t = blockIdx.x * 256 + threadIdx.x;
#pragma unroll
  for (int s = 0; s < 2; ++s) {
    int e = te[2 * t + s];
    int pos = atomicAdd(&ctrl[C_CUR + e], 1);
    ptok[pos] = t;
    pw[pos] = tw[2 * t + s];
  }
}

// ---- transpose+convert v2: W [E][R][C] fp32 -> out [E][C][R] fp16 ----
// 64c x 128r tile. In-register 4x4 transpose -> ds_write_b64 into 16B-chunk
// XOR-swizzled LDS (chunk = (r>>3)^(c&15)): conflict-free writes AND reads.
// Global: 256B read segments, 256B write segments. 16KB LDS -> 8 blocks/CU.
__global__ void k_transpose(const float* __restrict__ W, _Float16* __restrict__ out,
                            int R, int C) {
  __shared__ __align__(16) _Float16 lds[64 * 128];
  int e = blockIdx.z;
  const float* Wb = W + ((long)e * R + blockIdx.x * 128) * C + blockIdx.y * 64;
  _Float16* ob = out + ((long)e * C + blockIdx.y * 64) * R + blockIdx.x * 128;
  int tid = threadIdx.x;
  int l = tid & 63, w = tid >> 6;
  int c0 = (l & 15) * 4;
  int rq0 = (l >> 4) * 4 + w * 16;
#pragma unroll
  for (int rr = 0; rr < 2; ++rr) {
    int rq = rq0 + rr * 64;
    float4 v0 = *(const float4*)(Wb + (long)(rq + 0) * C + c0);
    float4 v1 = *(const float4*)(Wb + (long)(rq + 1) * C + c0);
    float4 v2 = *(const float4*)(Wb + (long)(rq + 2) * C + c0);
    float4 v3 = *(const float4*)(Wb + (long)(rq + 3) * C + c0);
    int rchunk = rq >> 3, rsub = rq & 7;
    {
      int c = c0 + 0;
      h4 hv = {(_Float16)v0.x, (_Float16)v1.x, (_Float16)v2.x, (_Float16)v3.x};
      *(h4*)&lds[c * 128 + ((rchunk ^ (c & 15)) << 3) + rsub] = hv;
    }
    {
      int c = c0 + 1;
      h4 hv = {(_Float16)v0.y, (_Float16)v1.y, (_Float16)v2.y, (_Float16)v3.y};
      *(h4*)&lds[c * 128 + ((rchunk ^ (c & 15)) << 3) + rsub] = hv;
    }
    {
      int c = c0 + 2;
      h4 hv = {(_Float16)v0.z, (_Float16)v1.z, (_Float16)v2.z, (_Float16)v3.z};
      *(h4*)&lds[c * 128 + ((rchunk ^ (c & 15)) << 3) + rsub] = hv;
    }
    {
      int c = c0 + 3;
      h4 hv = {(_Float16)v0.w, (_Float16)v1.w, (_Float16)v2.w, (_Float16)v3.w};
      *(h4*)&lds[c * 128 + ((rchunk ^ (c & 15)) << 3) + rsub] = hv;
    }
  }
  __syncthreads();
#pragma unroll
  for (int it = 0; it < 4; ++it) {
    int idx = it * 256 + tid;
    int c = idx >> 4, ch = idx & 15;
    h8 v = *(const h8*)&lds[c * 128 + ((ch ^ (c & 15)) << 3)];
    *(h8*)(ob + (long)c * R + ch * 8) = v;
  }
}

// ---- grouped GEMM: 256x256 tile, BK=64, 8 waves (2Mx4N), 8-phase schedule ----
// KP=1 everywhere (split-K reverted: atomic passes cost ~21us each).
// 1D grid, bijective XCD chunk swizzle, mt-fastest so co-resident blocks of an
// XCD share the same 512KB B K-slice in its L2.
// T3+T4: counted vmcnt(6) once per K-tile; T5: setprio around MFMA clusters.
// LDS 128 KiB: 2 dbuf x {A,B} x 2 halves x 128x64 fp16. XOR swizzle on global
// source chunk (c ^= r&7); linear global_load_lds dest; same XOR on ds_read.
template<int KD, int ND, int G1, int KP>
__global__ __launch_bounds__(512, 2)
void k_gemm(const _Float16* __restrict__ A, const _Float16* __restrict__ Wt,
            const float* __restrict__ bias, const int* __restrict__ ctrl,
            const int* __restrict__ ptok, const float* __restrict__ pw,
            _Float16* __restrict__ Hout, float* __restrict__ out) {
  __shared__ __align__(16) _Float16 sm[65536];   // 128 KB

  constexpr int NW = (ND / 256) * KP * MAXTILES;
  constexpr int QX = NW / 8;                     // chunk per XCD
  int bid = blockIdx.x;
  int wid = (bid & 7) * QX + (bid >> 3);         // bijective XCD chunk swizzle
  int mt = wid % MAXTILES;
  int g  = wid / MAXTILES;
  int kp = (KP > 1) ? (g % KP) : 0;
  int nb = g / KP;

  if (mt >= ctrl[C_NT]) return;
  int e  = ctrl[C_TE + mt];
  int p0 = ctrl[C_TP + mt];
  int n0 = nb * 256;
  long kbase = (long)kp * (KD / KP);
  int tid = threadIdx.x;
  int w = tid >> 6, l = tid & 63;
  int wm = w & 1, wn = w >> 1;           // 2 M-warps x 4 N-warps
  int ln15 = l & 15, lq = l >> 4;

  // ---- staging pointers: per (tensor, half, slot j) ----
  const _Float16* agp[4];   // [half*2+j]
  const _Float16* bgp[4];
#pragma unroll
  for (int h = 0; h < 2; ++h)
#pragma unroll
    for (int j = 0; j < 2; ++j) {
      int r = (w * 2 + j) * 8 + (l >> 3);          // row in half, 0..127
      int c = (l & 7) ^ (r & 7);
      long arow = G1 ? (long)ptok[p0 + h * 128 + r] : (long)(p0 + h * 128 + r);
      agp[h * 2 + j] = A + arow * KD + kbase + c * 8;
      bgp[h * 2 + j] = Wt + ((long)e * ND + n0 + h * 128 + r) * KD + kbase + c * 8;
    }

  // half ids: 0=A0 1=B0 2=A1 3=B1 (stage order within a tile)
  auto stageH = [&](int t, int half) {
    _Float16* dst = sm + (t & 1) * 32768 + (half & 1) * 16384 + (half >> 1) * 8192
                    + w * 1024;
    long koff = (long)t * 64;
    const _Float16* const* gp = (half & 1) ? bgp : agp;
#pragma unroll
    for (int j = 0; j < 2; ++j)
      async16(gp[(half >> 1) * 2 + j] + koff, dst + j * 512);
  };

  f4 acc[2][4][2][2];
#pragma unroll
  for (int mq = 0; mq < 2; ++mq)
#pragma unroll
    for (int i = 0; i < 4; ++i)
#pragma unroll
      for (int nq = 0; nq < 2; ++nq)
#pragma unroll
        for (int j = 0; j < 2; ++j) acc[mq][i][nq][j] = (f4){0.f, 0.f, 0.f, 0.f};

  h8 af[8], bf0[4], bf1[4];

  auto readA = [&](int d, int mq) {     // 8 x ds_read_b128
    const _Float16* Ab = sm + d * 32768 + mq * 8192;
#pragma unroll
    for (int i = 0; i < 4; ++i) {
      int rh = wm * 64 + i * 16 + ln15;
#pragma unroll
      for (int ks = 0; ks < 2; ++ks)
        af[i * 2 + ks] = *(const h8*)&Ab[rh * 64 + (((ks * 4 + lq)) ^ (rh & 7)) * 8];
    }
  };
  auto readB = [&](int d, int nq, h8* bf) {   // 4 x ds_read_b128
    const _Float16* Bb = sm + d * 32768 + 16384 + nq * 8192;
#pragma unroll
    for (int j = 0; j < 2; ++j) {
      int rh = wn * 32 + j * 16 + ln15;
#pragma unroll
      for (int ks = 0; ks < 2; ++ks)
        bf[j * 2 + ks] = *(const h8*)&Bb[rh * 64 + (((ks * 4 + lq)) ^ (rh & 7)) * 8];
    }
  };
  auto mfmaQ = [&](int mq, int nq, const h8* bf) {  // 16 MFMA = one C-quadrant
    __builtin_amdgcn_s_setprio(1);
#pragma unroll
    for (int ks = 0; ks < 2; ++ks)
#pragma unroll
      for (int i = 0; i < 4; ++i)
#pragma unroll
        for (int j = 0; j < 2; ++j)
          acc[mq][i][nq][j] = __builtin_amdgcn_mfma_f32_16x16x32_f16(
              af[i * 2 + ks], bf[j * 2 + ks], acc[mq][i][nq][j], 0, 0, 0);
    __builtin_amdgcn_s_setprio(0);
  };

  constexpr int KSTEPS = KD / 64 / KP;

  // prologue: tile0 (4 halves) + tile1 (3 halves) = 14 loads/wave in flight
  stageH(0, 0); stageH(0, 1); stageH(0, 2); stageH(0, 3);
  stageH(1, 0); stageH(1, 1); stageH(1, 2);
  asm volatile("s_waitcnt vmcnt(6)" ::: "memory");   // tile0 landed, 3 halves in flight
  __builtin_amdgcn_s_barrier();

#pragma unroll 2
  for (int t = 0; t < KSTEPS; ++t) {
    int d = t & 1;
    // P1: quadrant (mq0,nq0) — needs A0,B0 (earliest staged)
    readA(d, 0);
    readB(d, 0, bf0);
    if (t + 1 < KSTEPS) stageH(t + 1, 3);            // B1 of next tile
    __builtin_amdgcn_s_barrier();
    asm volatile("s_waitcnt lgkmcnt(0)" ::: "memory");
    mfmaQ(0, 0, bf0);
    __builtin_amdgcn_s_barrier();
    // P2: (mq0,nq1) — needs B1; A0 retired -> stage t+2 A0 in place
    readB(d, 1, bf1);
    if (t + 2 < KSTEPS) stageH(t + 2, 0);
    __builtin_amdgcn_s_barrier();
    asm volatile("s_waitcnt lgkmcnt(0)" ::: "memory");
    mfmaQ(0, 1, bf1);
    __builtin_amdgcn_s_barrier();
    // P3: (mq1,nq1) — needs A1; B0 retired -> stage t+2 B0
    readA(d, 1);
    if (t + 2 < KSTEPS) stageH(t + 2, 1);
    __builtin_amdgcn_s_barrier();
    asm volatile("s_waitcnt lgkmcnt(0)" ::: "memory");
    mfmaQ(1, 1, bf1);
    __builtin_amdgcn_s_barrier();
    // P4: (mq1,nq0) — reuses af/bf0; A1 retired -> stage t+2 A1; counted wait
    if (t + 2 < KSTEPS) stageH(t + 2, 2);
    if (t + 1 < KSTEPS) {
      if (t + 2 < KSTEPS) asm volatile("s_waitcnt vmcnt(6)" ::: "memory");
      else                asm volatile("s_waitcnt vmcnt(0)" ::: "memory");
    }
    __builtin_amdgcn_s_barrier();
    mfmaQ(1, 0, bf0);
    __builtin_amdgcn_s_barrier();
  }

  // ---- epilogue ----
  float bj[2][2];
#pragma unroll
  for (int nq = 0; nq < 2; ++nq)
#pragma unroll
    for (int j = 0; j < 2; ++j)
      bj[nq][j] = bias[e * ND + n0 + nq * 128 + wn * 32 + j * 16 + ln15];
  if (KP > 1 && kp != 0) {            // split-K: only part 0 adds bias
#pragma unroll
    for (int nq = 0; nq < 2; ++nq)
#pragma unroll
      for (int j = 0; j < 2; ++j) bj[nq][j] = 0.f;
  }

  if (G1) {
    // LDS-bounce (reuse sm): two 128-row halves, [128][264] fp16 padded
    _Float16* cs = sm;
#pragma unroll
    for (int mq = 0; mq < 2; ++mq) {
      if (mq) __syncthreads();
#pragma unroll
      for (int i = 0; i < 4; ++i)
#pragma unroll
        for (int reg = 0; reg < 4; ++reg) {
          int row = wm * 64 + i * 16 + lq * 4 + reg;
#pragma unroll
          for (int nq = 0; nq < 2; ++nq)
#pragma unroll
            for (int j = 0; j < 2; ++j)
              cs[row * 264 + nq * 128 + wn * 32 + j * 16 + ln15] =
                  (_Float16)fmaxf(acc[mq][i][nq][j][reg] + bj[nq][j], 0.f);
        }
      __syncthreads();
#pragma unroll
      for (int p = 0; p < 8; ++p) {
        int idx = p * 512 + tid;          // 128 rows x 32 h8-chunks
        int row = idx >> 5, ch = idx & 31;
        *(h8*)(Hout + (long)(p0 + mq * 128 + row) * DHID + n0 + ch * 8) =
            *(const h8*)&cs[row * 264 + ch * 8];
      }
    }
  } else {
#pragma unroll
    for (int mq = 0; mq < 2; ++mq)
#pragma unroll
      for (int i = 0; i < 4; ++i)
#pragma unroll
        for (int reg = 0; reg < 4; ++reg) {
          int p = p0 + mq * 128 + wm * 64 + i * 16 + lq * 4 + reg;
          float wgt = pw[p];
          if (wgt != 0.f) {
            int tk = ptok[p];
            float* orow = out + (long)tk * DOUT + n0;
#pragma unroll
            for (int nq = 0; nq < 2; ++nq)
#pragma unroll
              for (int j = 0; j < 2; ++j)
                atomicAdd(&orow[nq * 128 + wn * 32 + j * 16 + ln15],
                          wgt * (acc[mq][i][nq][j][reg] + bj[nq][j]));
          }
        }
  }
}

extern "C" void kernel_launch(void* const* d_in, const int* in_sizes, int n_in,
                              void* d_out, int out_size, void* d_ws, size_t ws_size,
                              hipStream_t stream) {
  const float* x  = (const float*)d_in[0];
  const float* Wg = (const float*)d_in[1];
  const float* W1 = (const float*)d_in[2];
  const float* b1 = (const float*)d_in[3];
  const float* W2 = (const float*)d_in[4];
  const float* b2 = (const float*)d_in[5];
  float* out = (float*)d_out;
  char* ws = (char*)d_ws;

  size_t WT_OFF = 0;                                   // fp16 W^T (reused W1 then W2)
  size_t H_OFF  = WT_OFF + (size_t)NEXP * DHID * DIN * 2;   // 134,217,728
  size_t X_OFF  = H_OFF  + (size_t)PADMAX * DHID * 2;       // +167,772,160
  size_t TE_OFF = X_OFF  + (size_t)NTOK * DIN * 2;          // +16,777,216
  size_t TW_OFF = TE_OFF + (size_t)NPAIR * 4;
  size_t PT_OFF = TW_OFF + (size_t)NPAIR * 4;
  size_t PW_OFF = PT_OFF + (size_t)PADMAX * 4;
  size_t CT_OFF = PW_OFF + (size_t)PADMAX * 4;
  size_t END    = CT_OFF + 4096;
  if (ws_size < END) {
    fprintf(stderr, "kernel_launch: ws too small (%zu < %zu)\n", ws_size, END);
    return;
  }
  _Float16* Wt  = (_Float16*)(ws + WT_OFF);
  _Float16* H   = (_Float16*)(ws + H_OFF);
  _Float16* x16 = (_Float16*)(ws + X_OFF);
  int*   te   = (int*)(ws + TE_OFF);
  float* tw   = (float*)(ws + TW_OFF);
  int*   pt   = (int*)(ws + PT_OFF);
  float* pw   = (float*)(ws + PW_OFF);
  int*   ctrl = (int*)(ws + CT_OFF);

  k_init<<<NTOK * DIN / (256 * 4), 256, 0, stream>>>(out, x, x16, pt, pw, ctrl);
  k_gate<<<NTOK / 4, 256, 0, stream>>>(x, Wg, te, tw, ctrl);
  k_scan<<<1, 256, 0, stream>>>(ctrl);
  k_assign<<<NTOK / 256, 256, 0, stream>>>(te, tw, ctrl, pt, pw);

  // W1 [E][1024][4096] -> Wt [E][4096][1024] fp16
  k_transpose<<<dim3(DIN / 128, DHID / 64, NEXP), 256, 0, stream>>>(W1, Wt, DIN, DHID);
  // G1: works = 16 nb * 80 mt = 1280
  k_gemm<DIN, DHID, 1, 1><<<dim3((DHID / 256) * MAXTILES), 512, 0, stream>>>(
      x16, Wt, b1, ctrl, pt, pw, H, nullptr);

  // W2 [E][4096][1024] -> Wt [E][1024][4096] fp16 (region reuse; stream-ordered)
  k_transpose<<<dim3(DHID / 128, DOUT / 64, NEXP), 256, 0, stream>>>(W2, Wt, DHID, DOUT);
  // G2: works = 4 nb * 80 mt = 320 (KP=1; split-K reverted)
  k_gemm<DHID, DOUT, 0, 1><<<dim3((DOUT / 256) * MAXTILES), 512, 0, stream>>>(
      H, Wt, b2, ctrl, pt, pw, nullptr, out);
}